// Round 5
// baseline (70.445 us; speedup 1.0000x reference)
//
#include <hip/hip_runtime.h>
#include <stdint.h>

// JointGNNEncoder fused 2-layer GCN, MI355X (gfx950).
// out[b] = mean_n ReLU( A @ ( ReLU( A @ (X W1) + b1 ) W2 ) + b2 )
// A@(X W) = (A@X) W ; A is tridiagonal (chains are index-contiguous).
// R5: LDS 66->51 KB for 3 blocks/CU (X' unioned into H buffer; ldsA dropped,
// tridiag read from global), launch_bounds(256,3), setprio around MFMA.

typedef __attribute__((ext_vector_type(8))) __bf16 bf16x8;
typedef __attribute__((ext_vector_type(4))) __bf16 bf16x4;
typedef __attribute__((ext_vector_type(4))) float f32x4;

// XOR bits 4..6 by row&7: spreads 16B slots of same-bank rows across banks
#define SWZ(row, byteoff) ((unsigned)(byteoff) ^ ((((unsigned)(row)) & 7u) << 4))

// ---------------------------------------------------------------------------
// prep: pack bf16 weights in per-fragment lane order (unchanged from R4).
// GEMM1 frag block idx = (hf*2 + ks): lane l holds
//   W1T(h = hf*16 + (l&15), k = ks*32 + (l>>4)*8 + j), j=0..7  -> ws[0,32K)
// GEMM2 frag block idx = ((of*4 + c)*2 + ks): lane l holds
//   W2T(o = of*16 + (l&15), f = c*64 + ks*32 + (l>>4)*8 + j)   -> ws[32K,160K)
// ---------------------------------------------------------------------------
__global__ void prep_kernel(const float* __restrict__ W1,
                            const float* __restrict__ W2,
                            unsigned char* __restrict__ ws) {
  int t = blockIdx.x * blockDim.x + threadIdx.x;
  bf16x8 v;
  if (t < 2048) {                     // GEMM1: 32 blocks * 64 lanes
    int blk = t >> 6, l = t & 63;
    int ks = blk & 1, hf = blk >> 1;
    int h  = hf * 16 + (l & 15);
    int k0 = ks * 32 + (l >> 4) * 8;
#pragma unroll
    for (int j = 0; j < 8; ++j) v[j] = (__bf16)W1[(k0 + j) * 256 + h];
    *(bf16x8*)(ws + t * 16) = v;
  } else if (t < 10240) {             // GEMM2: 128 blocks * 64 lanes
    int t2 = t - 2048;
    int blk = t2 >> 6, l = t2 & 63;
    int ks = blk & 1;
    int c  = (blk >> 1) & 3;
    int of = blk >> 3;
    int o  = of * 16 + (l & 15);
    int f0 = c * 64 + ks * 32 + (l >> 4) * 8;
#pragma unroll
    for (int j = 0; j < 8; ++j) v[j] = (__bf16)W2[(f0 + j) * 256 + o];
    *(bf16x8*)(ws + 32768 + t2 * 16) = v;
  }
}

// ---------------------------------------------------------------------------
// main fused kernel: 256 threads = 4 waves; block = 4 graphs = 96 rows.
// wave wid owns o-tile wid*64 (4 frags fi); m-tile = all 96 rows (6 frags fj).
// buf lifetimes: X' (96x128 swz) [barrA..barrB] ; H1/Z (96x512 swz) [after
// barrB .. end]. barrB separates the last X' read from the first H1 write.
// ---------------------------------------------------------------------------
__launch_bounds__(256, 3)
__global__ void gnn_kernel(const float* __restrict__ X,
                           const float* __restrict__ b1g,
                           const float* __restrict__ b2g,
                           const float* __restrict__ Ag,
                           const unsigned char* __restrict__ ws,
                           float* __restrict__ out) {
  __shared__ __align__(16) unsigned char buf[96 * 512];   // 48K: X' then H1/Z
  __shared__ __align__(16) float ldsB1[256];
  __shared__ __align__(16) float ldsB2[256];

  const int tid  = threadIdx.x;
  const int lane = tid & 63;
  const int wid  = tid >> 6;
  const int g0   = blockIdx.x * 4;
  const long row0 = (long)g0 * 24;

  ldsB1[tid] = b1g[tid];
  ldsB2[tid] = b2g[tid];

  const int r16   = lane & 15;
  const int kgrp  = (lane >> 4) * 8;
  const int lbyte = lane * 16;

  // prefetch GEMM1 weight fragments (global, packed lane order)
  bf16x8 af1[2][4];
#pragma unroll
  for (int ks = 0; ks < 2; ++ks)
#pragma unroll
    for (int fi = 0; fi < 4; ++fi)
      af1[ks][fi] = *(const bf16x8*)(ws + ((((wid * 4 + fi) * 2) + ks) << 10) + lbyte);

  // ---- X' = (A @ X) rows (tridiagonal mix) -> bf16 swizzled into buf[0,12K)
#pragma unroll
  for (int it = 0; it < 6; ++it) {
    int idx = tid + it * 256;            // 96 rows x 16 float4-chunks
    int m   = idx >> 4;
    int c4  = (idx & 15) * 4;
    int n   = m - (m / 24) * 24;
    const float* xr = X + (row0 + m) * 64 + c4;
    float wmid = Ag[n * 25];             // A[n][n]
    float wdn  = (n > 0)  ? Ag[n * 25 - 1] : 0.f;
    float wup  = (n < 23) ? Ag[n * 25 + 1] : 0.f;
    float4 xc = *(const float4*)xr;
    float ax = wmid * xc.x, ay = wmid * xc.y, az = wmid * xc.z, aw = wmid * xc.w;
    if (wdn != 0.f) {
      float4 xd = *(const float4*)(xr - 64);
      ax += wdn * xd.x; ay += wdn * xd.y; az += wdn * xd.z; aw += wdn * xd.w;
    }
    if (wup != 0.f) {
      float4 xu = *(const float4*)(xr + 64);
      ax += wup * xu.x; ay += wup * xu.y; az += wup * xu.z; aw += wup * xu.w;
    }
    bf16x4 p;
    p[0] = (__bf16)ax; p[1] = (__bf16)ay; p[2] = (__bf16)az; p[3] = (__bf16)aw;
    *(bf16x4*)(buf + SWZ(m, m * 128 + c4 * 2)) = p;
  }
  __syncthreads();   // barrA: X' ready (and ldsB1/B2 filled)

  f32x4 acc[4][6];
  const f32x4 z4 = {0.f, 0.f, 0.f, 0.f};
#pragma unroll
  for (int i = 0; i < 4; ++i)
#pragma unroll
    for (int j = 0; j < 6; ++j) acc[i][j] = z4;

  // ---- GEMM1: D[h][m] = W1T(h,k) * X'(m,k)^T, K=64
#pragma unroll
  for (int ks = 0; ks < 2; ++ks) {
    bf16x8 bf[6];
    int koff = (ks * 32 + kgrp) * 2;
#pragma unroll
    for (int fj = 0; fj < 6; ++fj) {
      int m = fj * 16 + r16;
      bf[fj] = *(const bf16x8*)(buf + SWZ(m, m * 128 + koff));
    }
    __builtin_amdgcn_s_setprio(1);
#pragma unroll
    for (int fi = 0; fi < 4; ++fi)
#pragma unroll
      for (int fj = 0; fj < 6; ++fj)
        acc[fi][fj] = __builtin_amdgcn_mfma_f32_16x16x32_bf16(af1[ks][fi], bf[fj], acc[fi][fj], 0, 0, 0);
    __builtin_amdgcn_s_setprio(0);
  }
  __syncthreads();   // barrB: all X' reads done; buf may be overwritten as H1

  // ---- epilogue1: bias + ReLU -> H1[m][h] bf16 (D: col=lane&15=m, row=(lane>>4)*4+reg=h)
  {
    int hr = (lane >> 4) * 4;
#pragma unroll
    for (int fi = 0; fi < 4; ++fi) {
      int h = wid * 64 + fi * 16 + hr;
      float4 bb = *(const float4*)&ldsB1[h];
#pragma unroll
      for (int fj = 0; fj < 6; ++fj) {
        int m = fj * 16 + r16;
        f32x4 v = acc[fi][fj];
        bf16x4 p;
        p[0] = (__bf16)fmaxf(v[0] + bb.x, 0.f);
        p[1] = (__bf16)fmaxf(v[1] + bb.y, 0.f);
        p[2] = (__bf16)fmaxf(v[2] + bb.z, 0.f);
        p[3] = (__bf16)fmaxf(v[3] + bb.w, 0.f);
        *(bf16x4*)(buf + SWZ(m, m * 512 + h * 2)) = p;
      }
    }
  }
  __syncthreads();   // barrC: H1 ready

  // ---- GEMM2: D[o][m] = W2T(o,f) * H1(m,f)^T, K=256
#pragma unroll
  for (int i = 0; i < 4; ++i)
#pragma unroll
    for (int j = 0; j < 6; ++j) acc[i][j] = z4;

  const unsigned char* w2p = ws + 32768;
#pragma unroll
  for (int c = 0; c < 4; ++c) {
#pragma unroll
    for (int ks = 0; ks < 2; ++ks) {
      bf16x8 af[4], bf[6];
      int foff = (c * 64 + ks * 32 + kgrp) * 2;
#pragma unroll
      for (int fi = 0; fi < 4; ++fi)
        af[fi] = *(const bf16x8*)(w2p + (((((wid * 4 + fi) * 4) + c) * 2 + ks) << 10) + lbyte);
#pragma unroll
      for (int fj = 0; fj < 6; ++fj) {
        int m = fj * 16 + r16;
        bf[fj] = *(const bf16x8*)(buf + SWZ(m, m * 512 + foff));
      }
      __builtin_amdgcn_s_setprio(1);
#pragma unroll
      for (int fi = 0; fi < 4; ++fi)
#pragma unroll
        for (int fj = 0; fj < 6; ++fj)
          acc[fi][fj] = __builtin_amdgcn_mfma_f32_16x16x32_bf16(af[fi], bf[fj], acc[fi][fj], 0, 0, 0);
      __builtin_amdgcn_s_setprio(0);
    }
  }
  __syncthreads();   // barrD: all H1 reads done before Z overwrites buf

  // ---- dump Z (pre-bias/ReLU) into buf as bf16 [m][o]
  {
    int orr = (lane >> 4) * 4;
#pragma unroll
    for (int fi = 0; fi < 4; ++fi) {
      int o = wid * 64 + fi * 16 + orr;
#pragma unroll
      for (int fj = 0; fj < 6; ++fj) {
        int m = fj * 16 + r16;
        f32x4 v = acc[fi][fj];
        bf16x4 p;
        p[0] = (__bf16)v[0]; p[1] = (__bf16)v[1];
        p[2] = (__bf16)v[2]; p[3] = (__bf16)v[3];
        *(bf16x4*)(buf + SWZ(m, m * 512 + o * 2)) = p;
      }
    }
  }
  __syncthreads();   // barrE: Z ready

  // ---- final: out[g][o] = 1/24 * sum_n ReLU( tri-mix(Z)[n][o] + b2[o] )
  {
    const int g  = wid;                  // one graph per wave
    const int o4 = lane * 4;
    const int rb = g * 24;
    float4 bt = *(const float4*)&ldsB2[o4];
    float bb[4] = {bt.x, bt.y, bt.z, bt.w};
    float s[4]  = {0.f, 0.f, 0.f, 0.f};
    float zp[4] = {0.f, 0.f, 0.f, 0.f};
    float zc[4], zn[4];
    {
      bf16x4 z = *(const bf16x4*)(buf + SWZ(rb, rb * 512 + o4 * 2));
      bf16x4 y = *(const bf16x4*)(buf + SWZ(rb + 1, (rb + 1) * 512 + o4 * 2));
#pragma unroll
      for (int j = 0; j < 4; ++j) { zc[j] = (float)z[j]; zn[j] = (float)y[j]; }
    }
#pragma unroll
    for (int nn = 0; nn < 24; ++nn) {
      const float w0 = Ag[nn * 25];      // uniform -> scalar loads
      float q[4];
#pragma unroll
      for (int j = 0; j < 4; ++j) q[j] = w0 * zc[j] + bb[j];
      if (nn > 0) {
        const float wd = Ag[nn * 25 - 1];
#pragma unroll
        for (int j = 0; j < 4; ++j) q[j] += wd * zp[j];
      }
      if (nn < 23) {
        const float wu = Ag[nn * 25 + 1];
#pragma unroll
        for (int j = 0; j < 4; ++j) q[j] += wu * zn[j];
      }
#pragma unroll
      for (int j = 0; j < 4; ++j) s[j] += fmaxf(q[j], 0.f);
#pragma unroll
      for (int j = 0; j < 4; ++j) { zp[j] = zc[j]; zc[j] = zn[j]; }
      if (nn < 22) {
        int r = rb + nn + 2;
        bf16x4 z = *(const bf16x4*)(buf + SWZ(r, r * 512 + o4 * 2));
#pragma unroll
        for (int j = 0; j < 4; ++j) zn[j] = (float)z[j];
      }
    }
    float4 r4;
    r4.x = s[0] * (1.f / 24.f);
    r4.y = s[1] * (1.f / 24.f);
    r4.z = s[2] * (1.f / 24.f);
    r4.w = s[3] * (1.f / 24.f);
    *(float4*)(out + (size_t)(g0 + g) * 256 + o4) = r4;
  }
}

extern "C" void kernel_launch(void* const* d_in, const int* in_sizes, int n_in,
                              void* d_out, int out_size, void* d_ws, size_t ws_size,
                              hipStream_t stream) {
  (void)n_in; (void)out_size; (void)ws_size;
  const float* X  = (const float*)d_in[0];
  const float* W1 = (const float*)d_in[1];
  const float* b1 = (const float*)d_in[2];
  const float* W2 = (const float*)d_in[3];
  const float* b2 = (const float*)d_in[4];
  const float* A  = (const float*)d_in[5];
  float* out = (float*)d_out;
  unsigned char* ws = (unsigned char*)d_ws;

  int B = in_sizes[0] / (24 * 64);   // 8192
  prep_kernel<<<40, 256, 0, stream>>>(W1, W2, ws);
  gnn_kernel<<<B / 4, 256, 0, stream>>>(X, b1, b2, A, ws, out);
}

// Round 6
// 63.971 us; speedup vs baseline: 1.1012x; 1.1012x over previous
//
#include <hip/hip_runtime.h>
#include <stdint.h>

// JointGNNEncoder fused 2-layer GCN, MI355X (gfx950).
// out[b] = mean_n ReLU( A @ ( ReLU( A @ (X W1) + b1 ) W2 ) + b2 )
// A@(X W) = (A@X) W ; A is tridiagonal (chains are index-contiguous).
// R6: R5 layout (51 KB LDS -> 3 blocks/CU) but launch_bounds back to (256,2):
// R5's (256,3) capped VGPR at 84 -> acc spilled to scratch (WRITE 8->68 MB,
// FETCH +18 MB, MfmaUtil down). Registers win over the occupancy hint.

typedef __attribute__((ext_vector_type(8))) __bf16 bf16x8;
typedef __attribute__((ext_vector_type(4))) __bf16 bf16x4;
typedef __attribute__((ext_vector_type(4))) float f32x4;

// XOR bits 4..6 by row&7: spreads 16B slots of same-bank rows across banks
#define SWZ(row, byteoff) ((unsigned)(byteoff) ^ ((((unsigned)(row)) & 7u) << 4))

// ---------------------------------------------------------------------------
// prep: pack bf16 weights in per-fragment lane order (unchanged from R4).
// GEMM1 frag block idx = (hf*2 + ks): lane l holds
//   W1T(h = hf*16 + (l&15), k = ks*32 + (l>>4)*8 + j), j=0..7  -> ws[0,32K)
// GEMM2 frag block idx = ((of*4 + c)*2 + ks): lane l holds
//   W2T(o = of*16 + (l&15), f = c*64 + ks*32 + (l>>4)*8 + j)   -> ws[32K,160K)
// ---------------------------------------------------------------------------
__global__ void prep_kernel(const float* __restrict__ W1,
                            const float* __restrict__ W2,
                            unsigned char* __restrict__ ws) {
  int t = blockIdx.x * blockDim.x + threadIdx.x;
  bf16x8 v;
  if (t < 2048) {                     // GEMM1: 32 blocks * 64 lanes
    int blk = t >> 6, l = t & 63;
    int ks = blk & 1, hf = blk >> 1;
    int h  = hf * 16 + (l & 15);
    int k0 = ks * 32 + (l >> 4) * 8;
#pragma unroll
    for (int j = 0; j < 8; ++j) v[j] = (__bf16)W1[(k0 + j) * 256 + h];
    *(bf16x8*)(ws + t * 16) = v;
  } else if (t < 10240) {             // GEMM2: 128 blocks * 64 lanes
    int t2 = t - 2048;
    int blk = t2 >> 6, l = t2 & 63;
    int ks = blk & 1;
    int c  = (blk >> 1) & 3;
    int of = blk >> 3;
    int o  = of * 16 + (l & 15);
    int f0 = c * 64 + ks * 32 + (l >> 4) * 8;
#pragma unroll
    for (int j = 0; j < 8; ++j) v[j] = (__bf16)W2[(f0 + j) * 256 + o];
    *(bf16x8*)(ws + 32768 + t2 * 16) = v;
  }
}

// ---------------------------------------------------------------------------
// main fused kernel: 256 threads = 4 waves; block = 4 graphs = 96 rows.
// wave wid owns o-tile wid*64 (4 frags fi); m-tile = all 96 rows (6 frags fj).
// buf lifetimes: X' (96x128 swz) [barrA..barrB] ; H1/Z (96x512 swz) after.
// ---------------------------------------------------------------------------
__launch_bounds__(256, 2)
__global__ void gnn_kernel(const float* __restrict__ X,
                           const float* __restrict__ b1g,
                           const float* __restrict__ b2g,
                           const float* __restrict__ Ag,
                           const unsigned char* __restrict__ ws,
                           float* __restrict__ out) {
  __shared__ __align__(16) unsigned char buf[96 * 512];   // 48K: X' then H1/Z
  __shared__ __align__(16) float ldsB1[256];
  __shared__ __align__(16) float ldsB2[256];

  const int tid  = threadIdx.x;
  const int lane = tid & 63;
  const int wid  = tid >> 6;
  const int g0   = blockIdx.x * 4;
  const long row0 = (long)g0 * 24;

  ldsB1[tid] = b1g[tid];
  ldsB2[tid] = b2g[tid];

  const int r16   = lane & 15;
  const int kgrp  = (lane >> 4) * 8;
  const int lbyte = lane * 16;

  // prefetch GEMM1 weight fragments (global, packed lane order)
  bf16x8 af1[2][4];
#pragma unroll
  for (int ks = 0; ks < 2; ++ks)
#pragma unroll
    for (int fi = 0; fi < 4; ++fi)
      af1[ks][fi] = *(const bf16x8*)(ws + ((((wid * 4 + fi) * 2) + ks) << 10) + lbyte);

  // ---- X' = (A @ X) rows (tridiagonal mix) -> bf16 swizzled into buf[0,12K)
#pragma unroll
  for (int it = 0; it < 6; ++it) {
    int idx = tid + it * 256;            // 96 rows x 16 float4-chunks
    int m   = idx >> 4;
    int c4  = (idx & 15) * 4;
    int n   = m - (m / 24) * 24;
    const float* xr = X + (row0 + m) * 64 + c4;
    float wmid = Ag[n * 25];             // A[n][n]
    float wdn  = (n > 0)  ? Ag[n * 25 - 1] : 0.f;
    float wup  = (n < 23) ? Ag[n * 25 + 1] : 0.f;
    float4 xc = *(const float4*)xr;
    float ax = wmid * xc.x, ay = wmid * xc.y, az = wmid * xc.z, aw = wmid * xc.w;
    if (wdn != 0.f) {
      float4 xd = *(const float4*)(xr - 64);
      ax += wdn * xd.x; ay += wdn * xd.y; az += wdn * xd.z; aw += wdn * xd.w;
    }
    if (wup != 0.f) {
      float4 xu = *(const float4*)(xr + 64);
      ax += wup * xu.x; ay += wup * xu.y; az += wup * xu.z; aw += wup * xu.w;
    }
    bf16x4 p;
    p[0] = (__bf16)ax; p[1] = (__bf16)ay; p[2] = (__bf16)az; p[3] = (__bf16)aw;
    *(bf16x4*)(buf + SWZ(m, m * 128 + c4 * 2)) = p;
  }
  __syncthreads();   // barrA: X' ready (and ldsB1/B2 filled)

  f32x4 acc[4][6];
  const f32x4 z4 = {0.f, 0.f, 0.f, 0.f};
#pragma unroll
  for (int i = 0; i < 4; ++i)
#pragma unroll
    for (int j = 0; j < 6; ++j) acc[i][j] = z4;

  // ---- GEMM1: D[h][m] = W1T(h,k) * X'(m,k)^T, K=64
#pragma unroll
  for (int ks = 0; ks < 2; ++ks) {
    bf16x8 bf[6];
    int koff = (ks * 32 + kgrp) * 2;
#pragma unroll
    for (int fj = 0; fj < 6; ++fj) {
      int m = fj * 16 + r16;
      bf[fj] = *(const bf16x8*)(buf + SWZ(m, m * 128 + koff));
    }
    __builtin_amdgcn_s_setprio(1);
#pragma unroll
    for (int fi = 0; fi < 4; ++fi)
#pragma unroll
      for (int fj = 0; fj < 6; ++fj)
        acc[fi][fj] = __builtin_amdgcn_mfma_f32_16x16x32_bf16(af1[ks][fi], bf[fj], acc[fi][fj], 0, 0, 0);
    __builtin_amdgcn_s_setprio(0);
  }
  __syncthreads();   // barrB: all X' reads done; buf may be overwritten as H1

  // ---- epilogue1: bias + ReLU -> H1[m][h] bf16 (D: col=lane&15=m, row=(lane>>4)*4+reg=h)
  {
    int hr = (lane >> 4) * 4;
#pragma unroll
    for (int fi = 0; fi < 4; ++fi) {
      int h = wid * 64 + fi * 16 + hr;
      float4 bb = *(const float4*)&ldsB1[h];
#pragma unroll
      for (int fj = 0; fj < 6; ++fj) {
        int m = fj * 16 + r16;
        f32x4 v = acc[fi][fj];
        bf16x4 p;
        p[0] = (__bf16)fmaxf(v[0] + bb.x, 0.f);
        p[1] = (__bf16)fmaxf(v[1] + bb.y, 0.f);
        p[2] = (__bf16)fmaxf(v[2] + bb.z, 0.f);
        p[3] = (__bf16)fmaxf(v[3] + bb.w, 0.f);
        *(bf16x4*)(buf + SWZ(m, m * 512 + h * 2)) = p;
      }
    }
  }
  __syncthreads();   // barrC: H1 ready

  // ---- GEMM2: D[o][m] = W2T(o,f) * H1(m,f)^T, K=256
#pragma unroll
  for (int i = 0; i < 4; ++i)
#pragma unroll
    for (int j = 0; j < 6; ++j) acc[i][j] = z4;

  const unsigned char* w2p = ws + 32768;
#pragma unroll
  for (int c = 0; c < 4; ++c) {
#pragma unroll
    for (int ks = 0; ks < 2; ++ks) {
      bf16x8 af[4], bf[6];
      int foff = (c * 64 + ks * 32 + kgrp) * 2;
#pragma unroll
      for (int fi = 0; fi < 4; ++fi)
        af[fi] = *(const bf16x8*)(w2p + (((((wid * 4 + fi) * 4) + c) * 2 + ks) << 10) + lbyte);
#pragma unroll
      for (int fj = 0; fj < 6; ++fj) {
        int m = fj * 16 + r16;
        bf[fj] = *(const bf16x8*)(buf + SWZ(m, m * 512 + foff));
      }
      __builtin_amdgcn_s_setprio(1);
#pragma unroll
      for (int fi = 0; fi < 4; ++fi)
#pragma unroll
        for (int fj = 0; fj < 6; ++fj)
          acc[fi][fj] = __builtin_amdgcn_mfma_f32_16x16x32_bf16(af[fi], bf[fj], acc[fi][fj], 0, 0, 0);
      __builtin_amdgcn_s_setprio(0);
    }
  }
  __syncthreads();   // barrD: all H1 reads done before Z overwrites buf

  // ---- dump Z (pre-bias/ReLU) into buf as bf16 [m][o]
  {
    int orr = (lane >> 4) * 4;
#pragma unroll
    for (int fi = 0; fi < 4; ++fi) {
      int o = wid * 64 + fi * 16 + orr;
#pragma unroll
      for (int fj = 0; fj < 6; ++fj) {
        int m = fj * 16 + r16;
        f32x4 v = acc[fi][fj];
        bf16x4 p;
        p[0] = (__bf16)v[0]; p[1] = (__bf16)v[1];
        p[2] = (__bf16)v[2]; p[3] = (__bf16)v[3];
        *(bf16x4*)(buf + SWZ(m, m * 512 + o * 2)) = p;
      }
    }
  }
  __syncthreads();   // barrE: Z ready

  // ---- final: out[g][o] = 1/24 * sum_n ReLU( tri-mix(Z)[n][o] + b2[o] )
  {
    const int g  = wid;                  // one graph per wave
    const int o4 = lane * 4;
    const int rb = g * 24;
    float4 bt = *(const float4*)&ldsB2[o4];
    float bb[4] = {bt.x, bt.y, bt.z, bt.w};
    float s[4]  = {0.f, 0.f, 0.f, 0.f};
    float zp[4] = {0.f, 0.f, 0.f, 0.f};
    float zc[4], zn[4];
    {
      bf16x4 z = *(const bf16x4*)(buf + SWZ(rb, rb * 512 + o4 * 2));
      bf16x4 y = *(const bf16x4*)(buf + SWZ(rb + 1, (rb + 1) * 512 + o4 * 2));
#pragma unroll
      for (int j = 0; j < 4; ++j) { zc[j] = (float)z[j]; zn[j] = (float)y[j]; }
    }
#pragma unroll
    for (int nn = 0; nn < 24; ++nn) {
      const float w0 = Ag[nn * 25];      // uniform -> scalar loads
      float q[4];
#pragma unroll
      for (int j = 0; j < 4; ++j) q[j] = w0 * zc[j] + bb[j];
      if (nn > 0) {
        const float wd = Ag[nn * 25 - 1];
#pragma unroll
        for (int j = 0; j < 4; ++j) q[j] += wd * zp[j];
      }
      if (nn < 23) {
        const float wu = Ag[nn * 25 + 1];
#pragma unroll
        for (int j = 0; j < 4; ++j) q[j] += wu * zn[j];
      }
#pragma unroll
      for (int j = 0; j < 4; ++j) s[j] += fmaxf(q[j], 0.f);
#pragma unroll
      for (int j = 0; j < 4; ++j) { zp[j] = zc[j]; zc[j] = zn[j]; }
      if (nn < 22) {
        int r = rb + nn + 2;
        bf16x4 z = *(const bf16x4*)(buf + SWZ(r, r * 512 + o4 * 2));
#pragma unroll
        for (int j = 0; j < 4; ++j) zn[j] = (float)z[j];
      }
    }
    float4 r4;
    r4.x = s[0] * (1.f / 24.f);
    r4.y = s[1] * (1.f / 24.f);
    r4.z = s[2] * (1.f / 24.f);
    r4.w = s[3] * (1.f / 24.f);
    *(float4*)(out + (size_t)(g0 + g) * 256 + o4) = r4;
  }
}

extern "C" void kernel_launch(void* const* d_in, const int* in_sizes, int n_in,
                              void* d_out, int out_size, void* d_ws, size_t ws_size,
                              hipStream_t stream) {
  (void)n_in; (void)out_size; (void)ws_size;
  const float* X  = (const float*)d_in[0];
  const float* W1 = (const float*)d_in[1];
  const float* b1 = (const float*)d_in[2];
  const float* W2 = (const float*)d_in[3];
  const float* b2 = (const float*)d_in[4];
  const float* A  = (const float*)d_in[5];
  float* out = (float*)d_out;
  unsigned char* ws = (unsigned char*)d_ws;

  int B = in_sizes[0] / (24 * 64);   // 8192
  prep_kernel<<<40, 256, 0, stream>>>(W1, W2, ws);
  gnn_kernel<<<B / 4, 256, 0, stream>>>(X, b1, b2, A, ws, out);
}

// Round 7
// 58.378 us; speedup vs baseline: 1.2067x; 1.0958x over previous
//
#include <hip/hip_runtime.h>
#include <stdint.h>

// JointGNNEncoder fused 2-layer GCN, MI355X (gfx950).
// out[b] = mean_n ReLU( A @ ( ReLU( A @ (X W1) + b1 ) W2 ) + b2 )
// A@(X W) = (A@X) W ; A is tridiagonal (chains are index-contiguous).
// R7: 512 threads / 8 waves (4 o-waves x 2 m-waves), 4 graphs/block.
// Halves per-wave MFMA/VALU work vs R6 -> shorter phases, 16 waves/CU
// (launch_bounds(512,4), VGPR cap 128 - no spill). GEMM2 weight fragments
// software-prefetched 1 step ahead. ldsX/ldsH separate (one less barrier).

typedef __attribute__((ext_vector_type(8))) __bf16 bf16x8;
typedef __attribute__((ext_vector_type(4))) __bf16 bf16x4;
typedef __attribute__((ext_vector_type(2))) __bf16 bf16x2;
typedef __attribute__((ext_vector_type(4))) float f32x4;

// XOR bits 4..6 by row&7: spreads 16B slots of same-bank rows across banks
#define SWZ(row, byteoff) ((unsigned)(byteoff) ^ ((((unsigned)(row)) & 7u) << 4))

// ---------------------------------------------------------------------------
// prep: pack bf16 weights in per-fragment lane order (unchanged from R4).
// GEMM1 frag block idx = (hf*2 + ks): lane l holds
//   W1T(h = hf*16 + (l&15), k = ks*32 + (l>>4)*8 + j), j=0..7  -> ws[0,32K)
// GEMM2 frag block idx = ((of*4 + c)*2 + ks): lane l holds
//   W2T(o = of*16 + (l&15), f = c*64 + ks*32 + (l>>4)*8 + j)   -> ws[32K,160K)
// ---------------------------------------------------------------------------
__global__ void prep_kernel(const float* __restrict__ W1,
                            const float* __restrict__ W2,
                            unsigned char* __restrict__ ws) {
  int t = blockIdx.x * blockDim.x + threadIdx.x;
  bf16x8 v;
  if (t < 2048) {                     // GEMM1: 32 blocks * 64 lanes
    int blk = t >> 6, l = t & 63;
    int ks = blk & 1, hf = blk >> 1;
    int h  = hf * 16 + (l & 15);
    int k0 = ks * 32 + (l >> 4) * 8;
#pragma unroll
    for (int j = 0; j < 8; ++j) v[j] = (__bf16)W1[(k0 + j) * 256 + h];
    *(bf16x8*)(ws + t * 16) = v;
  } else if (t < 10240) {             // GEMM2: 128 blocks * 64 lanes
    int t2 = t - 2048;
    int blk = t2 >> 6, l = t2 & 63;
    int ks = blk & 1;
    int c  = (blk >> 1) & 3;
    int of = blk >> 3;
    int o  = of * 16 + (l & 15);
    int f0 = c * 64 + ks * 32 + (l >> 4) * 8;
#pragma unroll
    for (int j = 0; j < 8; ++j) v[j] = (__bf16)W2[(f0 + j) * 256 + o];
    *(bf16x8*)(ws + 32768 + t2 * 16) = v;
  }
}

// ---------------------------------------------------------------------------
// main fused kernel: 512 threads = 8 waves; block = 4 graphs = 96 rows.
// wave (ow = wid&3, mw = wid>>2): o-tile ow*64 (4 fi), m-half mw*48 (3 fj).
// ---------------------------------------------------------------------------
__launch_bounds__(512, 4)
__global__ void gnn_kernel(const float* __restrict__ X,
                           const float* __restrict__ b1g,
                           const float* __restrict__ b2g,
                           const float* __restrict__ Ag,
                           const unsigned char* __restrict__ ws,
                           float* __restrict__ out) {
  __shared__ __align__(16) unsigned char ldsX[96 * 128];   // X' bf16 swz 12K
  __shared__ __align__(16) unsigned char ldsH[96 * 512];   // H1/Z bf16 swz 48K
  __shared__ __align__(16) float ldsB1[256];
  __shared__ __align__(16) float ldsB2[256];

  const int tid  = threadIdx.x;
  const int lane = tid & 63;
  const int wid  = tid >> 6;
  const int ow   = wid & 3;
  const int mw   = wid >> 2;
  const int g0   = blockIdx.x * 4;
  const long row0 = (long)g0 * 24;

  if (tid < 256) { ldsB1[tid] = b1g[tid]; ldsB2[tid] = b2g[tid]; }

  const int r16   = lane & 15;
  const int kgrp  = (lane >> 4) * 8;
  const int lbyte = lane * 16;

  // ---- X' = (A @ X) rows (tridiagonal mix) -> bf16 swizzled into ldsX
#pragma unroll
  for (int it = 0; it < 3; ++it) {
    int idx = tid + it * 512;            // 96 rows x 16 float4-chunks
    int m   = idx >> 4;
    int c4  = (idx & 15) * 4;
    int n   = m - (m / 24) * 24;
    const float* xr = X + (row0 + m) * 64 + c4;
    float wmid = Ag[n * 25];             // A[n][n]
    float wdn  = (n > 0)  ? Ag[n * 25 - 1] : 0.f;
    float wup  = (n < 23) ? Ag[n * 25 + 1] : 0.f;
    float4 xc = *(const float4*)xr;
    float ax = wmid * xc.x, ay = wmid * xc.y, az = wmid * xc.z, aw = wmid * xc.w;
    if (wdn != 0.f) {
      float4 xd = *(const float4*)(xr - 64);
      ax += wdn * xd.x; ay += wdn * xd.y; az += wdn * xd.z; aw += wdn * xd.w;
    }
    if (wup != 0.f) {
      float4 xu = *(const float4*)(xr + 64);
      ax += wup * xu.x; ay += wup * xu.y; az += wup * xu.z; aw += wup * xu.w;
    }
    bf16x4 p;
    p[0] = (__bf16)ax; p[1] = (__bf16)ay; p[2] = (__bf16)az; p[3] = (__bf16)aw;
    *(bf16x4*)(ldsX + SWZ(m, m * 128 + c4 * 2)) = p;
  }
  __syncthreads();   // barrA: X' + biases ready

  f32x4 acc[4][3];
  const f32x4 z4 = {0.f, 0.f, 0.f, 0.f};
#pragma unroll
  for (int i = 0; i < 4; ++i)
#pragma unroll
    for (int j = 0; j < 3; ++j) acc[i][j] = z4;

  // ---- GEMM1: D[h][m] = W1T(h,k) * X'(m,k)^T, K=64
#pragma unroll
  for (int ks = 0; ks < 2; ++ks) {
    bf16x8 af[4], bf[3];
    int koff = (ks * 32 + kgrp) * 2;
#pragma unroll
    for (int fi = 0; fi < 4; ++fi)
      af[fi] = *(const bf16x8*)(ws + ((((ow * 4 + fi) * 2) + ks) << 10) + lbyte);
#pragma unroll
    for (int fj = 0; fj < 3; ++fj) {
      int m = mw * 48 + fj * 16 + r16;
      bf[fj] = *(const bf16x8*)(ldsX + SWZ(m, m * 128 + koff));
    }
    __builtin_amdgcn_s_setprio(1);
#pragma unroll
    for (int fi = 0; fi < 4; ++fi)
#pragma unroll
      for (int fj = 0; fj < 3; ++fj)
        acc[fi][fj] = __builtin_amdgcn_mfma_f32_16x16x32_bf16(af[fi], bf[fj], acc[fi][fj], 0, 0, 0);
    __builtin_amdgcn_s_setprio(0);
  }

  // ---- epilogue1: bias + ReLU -> H1[m][h] bf16 (D: col=lane&15=m, row=(lane>>4)*4+reg=h)
  {
    int hr = (lane >> 4) * 4;
#pragma unroll
    for (int fi = 0; fi < 4; ++fi) {
      int h = ow * 64 + fi * 16 + hr;
      float4 bb = *(const float4*)&ldsB1[h];
#pragma unroll
      for (int fj = 0; fj < 3; ++fj) {
        int m = mw * 48 + fj * 16 + r16;
        f32x4 v = acc[fi][fj];
        bf16x4 p;
        p[0] = (__bf16)fmaxf(v[0] + bb.x, 0.f);
        p[1] = (__bf16)fmaxf(v[1] + bb.y, 0.f);
        p[2] = (__bf16)fmaxf(v[2] + bb.z, 0.f);
        p[3] = (__bf16)fmaxf(v[3] + bb.w, 0.f);
        *(bf16x4*)(ldsH + SWZ(m, m * 512 + h * 2)) = p;
      }
    }
  }
  __syncthreads();   // barrC: H1 ready

  // ---- GEMM2: D[o][m] = W2T(o,f) * H1(m,f)^T, K=256 (8 steps, prefetched)
#pragma unroll
  for (int i = 0; i < 4; ++i)
#pragma unroll
    for (int j = 0; j < 3; ++j) acc[i][j] = z4;

  const unsigned char* w2p = ws + 32768;
  bf16x8 afc[4];
#pragma unroll
  for (int fi = 0; fi < 4; ++fi)    // step 0 (c=0, ks=0)
    afc[fi] = *(const bf16x8*)(w2p + ((((ow * 4 + fi) * 4 + 0) * 2 + 0) << 10) + lbyte);

#pragma unroll
  for (int s = 0; s < 8; ++s) {
    const int c  = s >> 1;
    const int ks = s & 1;
    bf16x8 afn[4];
    if (s < 7) {
      const int c2  = (s + 1) >> 1;
      const int ks2 = (s + 1) & 1;
#pragma unroll
      for (int fi = 0; fi < 4; ++fi)
        afn[fi] = *(const bf16x8*)(w2p + ((((ow * 4 + fi) * 4 + c2) * 2 + ks2) << 10) + lbyte);
    }
    bf16x8 bf[3];
    int foff = (c * 64 + ks * 32 + kgrp) * 2;
#pragma unroll
    for (int fj = 0; fj < 3; ++fj) {
      int m = mw * 48 + fj * 16 + r16;
      bf[fj] = *(const bf16x8*)(ldsH + SWZ(m, m * 512 + foff));
    }
    __builtin_amdgcn_s_setprio(1);
#pragma unroll
    for (int fi = 0; fi < 4; ++fi)
#pragma unroll
      for (int fj = 0; fj < 3; ++fj)
        acc[fi][fj] = __builtin_amdgcn_mfma_f32_16x16x32_bf16(afc[fi], bf[fj], acc[fi][fj], 0, 0, 0);
    __builtin_amdgcn_s_setprio(0);
#pragma unroll
    for (int fi = 0; fi < 4; ++fi) afc[fi] = afn[fi];
  }
  __syncthreads();   // barrD: all H1 reads done before Z overwrites ldsH

  // ---- dump Z (pre-bias/ReLU) into ldsH as bf16 [m][o]
  {
    int orr = (lane >> 4) * 4;
#pragma unroll
    for (int fi = 0; fi < 4; ++fi) {
      int o = ow * 64 + fi * 16 + orr;
#pragma unroll
      for (int fj = 0; fj < 3; ++fj) {
        int m = mw * 48 + fj * 16 + r16;
        f32x4 v = acc[fi][fj];
        bf16x4 p;
        p[0] = (__bf16)v[0]; p[1] = (__bf16)v[1];
        p[2] = (__bf16)v[2]; p[3] = (__bf16)v[3];
        *(bf16x4*)(ldsH + SWZ(m, m * 512 + o * 2)) = p;
      }
    }
  }
  __syncthreads();   // barrE: Z ready

  // ---- final: out[g][o] = 1/24 * sum_n ReLU( tri-mix(Z)[n][o] + b2[o] )
  // 2 waves per graph: g = wid&3, o-half = (wid>>2)*128; lane covers 2 o.
  {
    const int g  = wid & 3;
    const int o2 = (wid >> 2) * 128 + lane * 2;
    const int rb = g * 24;
    float bb[2] = { ldsB2[o2], ldsB2[o2 + 1] };
    float s[2]  = {0.f, 0.f};
    float zp[2] = {0.f, 0.f};
    float zc[2], zn[2];
    {
      bf16x2 z = *(const bf16x2*)(ldsH + SWZ(rb, rb * 512 + o2 * 2));
      bf16x2 y = *(const bf16x2*)(ldsH + SWZ(rb + 1, (rb + 1) * 512 + o2 * 2));
      zc[0] = (float)z[0]; zc[1] = (float)z[1];
      zn[0] = (float)y[0]; zn[1] = (float)y[1];
    }
#pragma unroll
    for (int nn = 0; nn < 24; ++nn) {
      const float w0 = Ag[nn * 25];      // uniform -> scalar loads
      float q[2];
#pragma unroll
      for (int j = 0; j < 2; ++j) q[j] = w0 * zc[j] + bb[j];
      if (nn > 0) {
        const float wd = Ag[nn * 25 - 1];
#pragma unroll
        for (int j = 0; j < 2; ++j) q[j] += wd * zp[j];
      }
      if (nn < 23) {
        const float wu = Ag[nn * 25 + 1];
#pragma unroll
        for (int j = 0; j < 2; ++j) q[j] += wu * zn[j];
      }
#pragma unroll
      for (int j = 0; j < 2; ++j) s[j] += fmaxf(q[j], 0.f);
#pragma unroll
      for (int j = 0; j < 2; ++j) { zp[j] = zc[j]; zc[j] = zn[j]; }
      if (nn < 22) {
        int r = rb + nn + 2;
        bf16x2 z = *(const bf16x2*)(ldsH + SWZ(r, r * 512 + o2 * 2));
        zn[0] = (float)z[0]; zn[1] = (float)z[1];
      }
    }
    float2 r2;
    r2.x = s[0] * (1.f / 24.f);
    r2.y = s[1] * (1.f / 24.f);
    *(float2*)(out + (size_t)(g0 + g) * 256 + o2) = r2;
  }
}

extern "C" void kernel_launch(void* const* d_in, const int* in_sizes, int n_in,
                              void* d_out, int out_size, void* d_ws, size_t ws_size,
                              hipStream_t stream) {
  (void)n_in; (void)out_size; (void)ws_size;
  const float* X  = (const float*)d_in[0];
  const float* W1 = (const float*)d_in[1];
  const float* b1 = (const float*)d_in[2];
  const float* W2 = (const float*)d_in[3];
  const float* b2 = (const float*)d_in[4];
  const float* A  = (const float*)d_in[5];
  float* out = (float*)d_out;
  unsigned char* ws = (unsigned char*)d_ws;

  int B = in_sizes[0] / (24 * 64);   // 8192
  prep_kernel<<<40, 256, 0, stream>>>(W1, W2, ws);
  gnn_kernel<<<B / 4, 512, 0, stream>>>(X, b1, b2, A, ws, out);
}

// Round 8
// 56.997 us; speedup vs baseline: 1.2359x; 1.0242x over previous
//
#include <hip/hip_runtime.h>
#include <stdint.h>

// JointGNNEncoder fused 2-layer GCN, MI355X (gfx950).
// out[b] = mean_n ReLU( A @ ( ReLU( A @ (X W1) + b1 ) W2 ) + b2 )
// A@(X W) = (A@X) W ; A is tridiagonal (chains are index-contiguous).
// R8: GEMM2 operands swapped -> D[m][o]: each lane holds 4 consecutive node
// rows, so layer-2 tri-mix + bias + ReLU + mean-pool run fully in registers
// (6 shfl + 2 shfl_xor per fi). Z-dump, 24-iter serial tail, and 2 barriers
// deleted; kernel has 2 barriers total.

typedef __attribute__((ext_vector_type(8))) __bf16 bf16x8;
typedef __attribute__((ext_vector_type(4))) __bf16 bf16x4;
typedef __attribute__((ext_vector_type(4))) float f32x4;

// XOR bits 4..6 by row&7: spreads 16B slots of same-bank rows across banks
#define SWZ(row, byteoff) ((unsigned)(byteoff) ^ ((((unsigned)(row)) & 7u) << 4))

// ---------------------------------------------------------------------------
// prep: pack bf16 weights in per-fragment lane order (unchanged from R4).
// GEMM1 frag block idx = (hf*2 + ks): lane l holds
//   W1T(h = hf*16 + (l&15), k = ks*32 + (l>>4)*8 + j), j=0..7  -> ws[0,32K)
// GEMM2 frag block idx = ((of*4 + c)*2 + ks): lane l holds
//   W2T(o = of*16 + (l&15), f = c*64 + ks*32 + (l>>4)*8 + j)   -> ws[32K,160K)
// ---------------------------------------------------------------------------
__global__ void prep_kernel(const float* __restrict__ W1,
                            const float* __restrict__ W2,
                            unsigned char* __restrict__ ws) {
  int t = blockIdx.x * blockDim.x + threadIdx.x;
  bf16x8 v;
  if (t < 2048) {                     // GEMM1: 32 blocks * 64 lanes
    int blk = t >> 6, l = t & 63;
    int ks = blk & 1, hf = blk >> 1;
    int h  = hf * 16 + (l & 15);
    int k0 = ks * 32 + (l >> 4) * 8;
#pragma unroll
    for (int j = 0; j < 8; ++j) v[j] = (__bf16)W1[(k0 + j) * 256 + h];
    *(bf16x8*)(ws + t * 16) = v;
  } else if (t < 10240) {             // GEMM2: 128 blocks * 64 lanes
    int t2 = t - 2048;
    int blk = t2 >> 6, l = t2 & 63;
    int ks = blk & 1;
    int c  = (blk >> 1) & 3;
    int of = blk >> 3;
    int o  = of * 16 + (l & 15);
    int f0 = c * 64 + ks * 32 + (l >> 4) * 8;
#pragma unroll
    for (int j = 0; j < 8; ++j) v[j] = (__bf16)W2[(f0 + j) * 256 + o];
    *(bf16x8*)(ws + 32768 + t2 * 16) = v;
  }
}

// ---------------------------------------------------------------------------
// main fused kernel: 512 threads = 8 waves; block = 4 graphs = 96 rows.
// wave (ow = wid&3, mw = wid>>2): o-tile ow*64 (4 fi), m-half mw*48 (3 fj).
// ---------------------------------------------------------------------------
__launch_bounds__(512, 4)
__global__ void gnn_kernel(const float* __restrict__ X,
                           const float* __restrict__ b1g,
                           const float* __restrict__ b2g,
                           const float* __restrict__ Ag,
                           const unsigned char* __restrict__ ws,
                           float* __restrict__ out) {
  __shared__ __align__(16) unsigned char ldsX[96 * 128];   // X' bf16 swz 12K
  __shared__ __align__(16) unsigned char ldsH[96 * 512];   // H1 bf16 swz 48K
  __shared__ __align__(16) float ldsB1[256];
  __shared__ __align__(16) float ldsB2[256];
  __shared__ __align__(16) float wdT[24];   // A[n][n-1], 0 at n=0
  __shared__ __align__(16) float w0T[24];   // A[n][n]
  __shared__ __align__(16) float wuT[24];   // A[n][n+1], 0 at n=23

  const int tid  = threadIdx.x;
  const int lane = tid & 63;
  const int wid  = tid >> 6;
  const int ow   = wid & 3;
  const int mw   = wid >> 2;
  const int g0   = blockIdx.x * 4;
  const long row0 = (long)g0 * 24;

  if (tid < 256) { ldsB1[tid] = b1g[tid]; ldsB2[tid] = b2g[tid]; }
  if (tid < 24) {
    wdT[tid] = tid > 0  ? Ag[tid * 25 - 1] : 0.f;
    w0T[tid] = Ag[tid * 25];
    wuT[tid] = tid < 23 ? Ag[tid * 25 + 1] : 0.f;
  }

  const int r16   = lane & 15;
  const int kgrp  = (lane >> 4) * 8;
  const int lbyte = lane * 16;

  // ---- X' = (A @ X) rows (tridiagonal mix) -> bf16 swizzled into ldsX
#pragma unroll
  for (int it = 0; it < 3; ++it) {
    int idx = tid + it * 512;            // 96 rows x 16 float4-chunks
    int m   = idx >> 4;
    int c4  = (idx & 15) * 4;
    int n   = m - (m / 24) * 24;
    const float* xr = X + (row0 + m) * 64 + c4;
    float wmid = Ag[n * 25];             // A[n][n]
    float wdn  = (n > 0)  ? Ag[n * 25 - 1] : 0.f;
    float wup  = (n < 23) ? Ag[n * 25 + 1] : 0.f;
    float4 xc = *(const float4*)xr;
    float ax = wmid * xc.x, ay = wmid * xc.y, az = wmid * xc.z, aw = wmid * xc.w;
    if (wdn != 0.f) {
      float4 xd = *(const float4*)(xr - 64);
      ax += wdn * xd.x; ay += wdn * xd.y; az += wdn * xd.z; aw += wdn * xd.w;
    }
    if (wup != 0.f) {
      float4 xu = *(const float4*)(xr + 64);
      ax += wup * xu.x; ay += wup * xu.y; az += wup * xu.z; aw += wup * xu.w;
    }
    bf16x4 p;
    p[0] = (__bf16)ax; p[1] = (__bf16)ay; p[2] = (__bf16)az; p[3] = (__bf16)aw;
    *(bf16x4*)(ldsX + SWZ(m, m * 128 + c4 * 2)) = p;
  }
  __syncthreads();   // barrA: X' + biases + coeff tables ready

  f32x4 acc[4][3];
  const f32x4 z4 = {0.f, 0.f, 0.f, 0.f};
#pragma unroll
  for (int i = 0; i < 4; ++i)
#pragma unroll
    for (int j = 0; j < 3; ++j) acc[i][j] = z4;

  // ---- GEMM1: D[h][m] = W1T(h,k) * X'(m,k)^T, K=64
#pragma unroll
  for (int ks = 0; ks < 2; ++ks) {
    bf16x8 af[4], bf[3];
    int koff = (ks * 32 + kgrp) * 2;
#pragma unroll
    for (int fi = 0; fi < 4; ++fi)
      af[fi] = *(const bf16x8*)(ws + ((((ow * 4 + fi) * 2) + ks) << 10) + lbyte);
#pragma unroll
    for (int fj = 0; fj < 3; ++fj) {
      int m = mw * 48 + fj * 16 + r16;
      bf[fj] = *(const bf16x8*)(ldsX + SWZ(m, m * 128 + koff));
    }
    __builtin_amdgcn_s_setprio(1);
#pragma unroll
    for (int fi = 0; fi < 4; ++fi)
#pragma unroll
      for (int fj = 0; fj < 3; ++fj)
        acc[fi][fj] = __builtin_amdgcn_mfma_f32_16x16x32_bf16(af[fi], bf[fj], acc[fi][fj], 0, 0, 0);
    __builtin_amdgcn_s_setprio(0);
  }

  // ---- epilogue1: bias + ReLU -> H1[m][h] bf16 (D: col=lane&15=m, row=(lane>>4)*4+reg=h)
  {
    int hr = (lane >> 4) * 4;
#pragma unroll
    for (int fi = 0; fi < 4; ++fi) {
      int h = ow * 64 + fi * 16 + hr;
      float4 bb = *(const float4*)&ldsB1[h];
#pragma unroll
      for (int fj = 0; fj < 3; ++fj) {
        int m = mw * 48 + fj * 16 + r16;
        f32x4 v = acc[fi][fj];
        bf16x4 p;
        p[0] = (__bf16)fmaxf(v[0] + bb.x, 0.f);
        p[1] = (__bf16)fmaxf(v[1] + bb.y, 0.f);
        p[2] = (__bf16)fmaxf(v[2] + bb.z, 0.f);
        p[3] = (__bf16)fmaxf(v[3] + bb.w, 0.f);
        *(bf16x4*)(ldsH + SWZ(m, m * 512 + h * 2)) = p;
      }
    }
  }
  __syncthreads();   // barrB: H1 ready

  // ---- GEMM2 (operands swapped): D[m][o] = H1(m,f) * W2T(o,f)^T, K=256
  // lane holds m = mw*48 + fj*16 + (lane>>4)*4 + r  (4 consecutive rows!),
  // o = ow*64 + fi*16 + (lane&15).
  f32x4 acc2[3][4];
#pragma unroll
  for (int j = 0; j < 3; ++j)
#pragma unroll
    for (int i = 0; i < 4; ++i) acc2[j][i] = z4;

  const unsigned char* w2p = ws + 32768;
  bf16x8 afc[4];
#pragma unroll
  for (int fi = 0; fi < 4; ++fi)    // step 0 (c=0, ks=0)
    afc[fi] = *(const bf16x8*)(w2p + ((((ow * 4 + fi) * 4 + 0) * 2 + 0) << 10) + lbyte);

#pragma unroll
  for (int s = 0; s < 8; ++s) {
    const int c  = s >> 1;
    const int ks = s & 1;
    bf16x8 afn[4];
    if (s < 7) {
      const int c2  = (s + 1) >> 1;
      const int ks2 = (s + 1) & 1;
#pragma unroll
      for (int fi = 0; fi < 4; ++fi)
        afn[fi] = *(const bf16x8*)(w2p + ((((ow * 4 + fi) * 4 + c2) * 2 + ks2) << 10) + lbyte);
    }
    bf16x8 bf[3];
    int foff = (c * 64 + ks * 32 + kgrp) * 2;
#pragma unroll
    for (int fj = 0; fj < 3; ++fj) {
      int m = mw * 48 + fj * 16 + r16;
      bf[fj] = *(const bf16x8*)(ldsH + SWZ(m, m * 512 + foff));
    }
    __builtin_amdgcn_s_setprio(1);
#pragma unroll
    for (int fj = 0; fj < 3; ++fj)
#pragma unroll
      for (int fi = 0; fi < 4; ++fi)
        acc2[fj][fi] = __builtin_amdgcn_mfma_f32_16x16x32_bf16(bf[fj], afc[fi], acc2[fj][fi], 0, 0, 0);
    __builtin_amdgcn_s_setprio(0);
#pragma unroll
    for (int fi = 0; fi < 4; ++fi) afc[fi] = afn[fi];
  }
  // no barrier needed: no further LDS writes; everything below is in-register

  // ---- final: in-register tri-mix + bias + ReLU + mean-pool over 24 nodes.
  // acc2[fj][fi][r] = Z[m][o], m-local lm = fj*16 + grp*4 + r (grp = lane>>4),
  // graph = (lm >= 24), n = lm % 24. Edge weights wdT[0] = wuT[23] = 0 kill
  // cross-graph garbage automatically.
  {
    const int grp = lane >> 4;
    const int l16 = lane & 15;
    const int src_up = (lane - 16) & 63;   // receive value of lane-16
    const int src_dn = (lane + 16) & 63;   // receive value of lane+16
#pragma unroll
    for (int fi = 0; fi < 4; ++fi) {
      const int o = ow * 64 + fi * 16 + l16;
      const float b2v = ldsB2[o];
      float s3[3], s0[3];
#pragma unroll
      for (int fj = 0; fj < 3; ++fj) {
        s3[fj] = __shfl(acc2[fj][fi][3], src_up);   // Z[lm-1] candidate for r=0
        s0[fj] = __shfl(acc2[fj][fi][0], src_dn);   // Z[lm+1] candidate for r=3
      }
      float p0 = 0.f, p1 = 0.f;
#pragma unroll
      for (int fj = 0; fj < 3; ++fj) {
        const int lmb = fj * 16 + grp * 4;
        const int nb  = (lmb < 24) ? lmb : lmb - 24;
        f32x4 wd4 = *(const f32x4*)&wdT[nb];
        f32x4 w04 = *(const f32x4*)&w0T[nb];
        f32x4 wu4 = *(const f32x4*)&wuT[nb];
        f32x4 v = acc2[fj][fi];
        float zl0 = s3[fj], zr3 = s0[fj];
        if (fj > 0 && grp == 0) zl0 = s3[fj - 1];   // cross-frag left neighbor
        if (fj < 2 && grp == 3) zr3 = s0[fj + 1];   // cross-frag right neighbor
        float q0 = b2v + wd4[0] * zl0 + w04[0] * v[0] + wu4[0] * v[1];
        float q1 = b2v + wd4[1] * v[0] + w04[1] * v[1] + wu4[1] * v[2];
        float q2 = b2v + wd4[2] * v[1] + w04[2] * v[2] + wu4[2] * v[3];
        float q3 = b2v + wd4[3] * v[2] + w04[3] * v[3] + wu4[3] * zr3;
        float qs = fmaxf(q0, 0.f) + fmaxf(q1, 0.f) +
                   fmaxf(q2, 0.f) + fmaxf(q3, 0.f);
        if (fj == 0) p0 += qs;
        else if (fj == 2) p1 += qs;
        else { bool low = grp < 2; p0 += low ? qs : 0.f; p1 += low ? 0.f : qs; }
      }
      // pool across the 4 row-groups (same l16 = same o)
      p0 += __shfl_xor(p0, 16); p0 += __shfl_xor(p0, 32);
      p1 += __shfl_xor(p1, 16); p1 += __shfl_xor(p1, 32);
      if (grp == 0) out[(size_t)(g0 + 2 * mw)     * 256 + o] = p0 * (1.f / 24.f);
      if (grp == 1) out[(size_t)(g0 + 2 * mw + 1) * 256 + o] = p1 * (1.f / 24.f);
    }
  }
}

extern "C" void kernel_launch(void* const* d_in, const int* in_sizes, int n_in,
                              void* d_out, int out_size, void* d_ws, size_t ws_size,
                              hipStream_t stream) {
  (void)n_in; (void)out_size; (void)ws_size;
  const float* X  = (const float*)d_in[0];
  const float* W1 = (const float*)d_in[1];
  const float* b1 = (const float*)d_in[2];
  const float* W2 = (const float*)d_in[3];
  const float* b2 = (const float*)d_in[4];
  const float* A  = (const float*)d_in[5];
  float* out = (float*)d_out;
  unsigned char* ws = (unsigned char*)d_ws;

  int B = in_sizes[0] / (24 * 64);   // 8192
  prep_kernel<<<40, 256, 0, stream>>>(W1, W2, ws);
  gnn_kernel<<<B / 4, 512, 0, stream>>>(X, b1, b2, A, ws, out);
}